// Round 1
// baseline (1192.474 us; speedup 1.0000x reference)
//
#include <hip/hip_runtime.h>
#include <cstdint>

namespace {

constexpr int kS   = 2048;
constexpr int kNH  = 16;
constexpr int kHD  = 64;
constexpr int kH   = 1024;
constexpr int kB   = 2;
constexpr int kWin = 32;
constexpr int kNBlk = kS / kWin;  // 64

// ---------------------------------------------------------------------------
// GEMM:  C = A @ W^T + bias
//   A [M,K] row-major, W [N,K] row-major (torch Linear weight), bias [N]
//   permute==0: C is [M,N] row-major
//   permute==1: C scattered to QKV layout [B, NH, S, HD]
// Tiles: 128x128x32, 256 threads, 8x8 microtile (rows ty*4 & 64+ty*4,
// cols tx*4 & 64+tx*4 so LDS b128 reads are <=2-way conflicted = free).
// ---------------------------------------------------------------------------
constexpr int BM = 128, BN = 128, BK = 32;

__global__ __launch_bounds__(256) void gemm_nt(
    const float* __restrict__ A, const float* __restrict__ W,
    const float* __restrict__ bias, float* __restrict__ C,
    int M, int N, int K, int permute)
{
  __shared__ float As[BK][BM + 4];  // stride 132 floats = 528B (16B aligned)
  __shared__ float Ws[BK][BN + 4];
  const int tid = threadIdx.x;
  const int bm = blockIdx.y * BM;
  const int bn = blockIdx.x * BN;
  const int tx = tid & 15;   // N direction
  const int ty = tid >> 4;   // M direction

  float acc[8][8];
#pragma unroll
  for (int i = 0; i < 8; ++i)
#pragma unroll
    for (int j = 0; j < 8; ++j) acc[i][j] = 0.f;

  const int lrow = tid >> 3;       // 0..31
  const int lk   = (tid & 7) << 2; // 0,4,...,28  (float4 col within 32-wide k-tile)

  for (int k0 = 0; k0 < K; k0 += BK) {
#pragma unroll
    for (int r = 0; r < 4; ++r) {
      const int row = lrow + r * 32;
      const float4 av = *(const float4*)(A + (size_t)(bm + row) * K + (k0 + lk));
      As[lk + 0][row] = av.x;
      As[lk + 1][row] = av.y;
      As[lk + 2][row] = av.z;
      As[lk + 3][row] = av.w;
      const float4 wv = *(const float4*)(W + (size_t)(bn + row) * K + (k0 + lk));
      Ws[lk + 0][row] = wv.x;
      Ws[lk + 1][row] = wv.y;
      Ws[lk + 2][row] = wv.z;
      Ws[lk + 3][row] = wv.w;
    }
    __syncthreads();
#pragma unroll
    for (int k = 0; k < BK; ++k) {
      const float4 a0 = *(const float4*)&As[k][ty * 4];
      const float4 a1 = *(const float4*)&As[k][64 + ty * 4];
      const float4 b0 = *(const float4*)&Ws[k][tx * 4];
      const float4 b1 = *(const float4*)&Ws[k][64 + tx * 4];
      const float a[8] = {a0.x, a0.y, a0.z, a0.w, a1.x, a1.y, a1.z, a1.w};
      const float b[8] = {b0.x, b0.y, b0.z, b0.w, b1.x, b1.y, b1.z, b1.w};
#pragma unroll
      for (int i = 0; i < 8; ++i)
#pragma unroll
        for (int j = 0; j < 8; ++j) acc[i][j] = fmaf(a[i], b[j], acc[i][j]);
    }
    __syncthreads();
  }

#pragma unroll
  for (int jg = 0; jg < 2; ++jg) {
    const int col = bn + jg * 64 + tx * 4;
    const float4 bv = *(const float4*)(bias + col);
#pragma unroll
    for (int i = 0; i < 8; ++i) {
      const int row = bm + (i >> 2) * 64 + ty * 4 + (i & 3);
      float4 o;
      o.x = acc[i][jg * 4 + 0] + bv.x;
      o.y = acc[i][jg * 4 + 1] + bv.y;
      o.z = acc[i][jg * 4 + 2] + bv.z;
      o.w = acc[i][jg * 4 + 3] + bv.w;
      if (permute) {
        // row = b*2048 + s ; col = h*64 + d  -> [B, NH, S, HD]
        const int b = row >> 11;
        const int s = row & 2047;
        const int h = col >> 6;
        const int d = col & 63;
        *(float4*)(C + (((size_t)(b * kNH + h) * kS + s) * kHD + d)) = o;
      } else {
        *(float4*)(C + (size_t)row * N + col) = o;
      }
    }
  }
}

// ---------------------------------------------------------------------------
// vtotal[bh][d] = sum_s v[bh][s][d]   (v in [B*NH, S, HD] layout)
// ---------------------------------------------------------------------------
__global__ __launch_bounds__(256) void vsum_kernel(const float* __restrict__ v,
                                                   float* __restrict__ vtotal) {
  __shared__ float red[4][64];
  const int bh = blockIdx.x;
  const int d  = threadIdx.x & 63;
  const int c  = threadIdx.x >> 6;
  const float* base = v + (size_t)bh * kS * kHD + (size_t)c * 512 * kHD + d;
  float s = 0.f;
#pragma unroll 8
  for (int i = 0; i < 512; ++i) s += base[(size_t)i * kHD];
  red[c][d] = s;
  __syncthreads();
  if (c == 0) {
    vtotal[bh * kHD + d] = red[0][d] + red[1][d] + red[2][d] + red[3][d];
  }
}

// ---------------------------------------------------------------------------
// Attention, one workgroup per (b, h, qblock).
// Exploits: masked (future-block) scores are 0 -> exp=1, so
//   num_i = sum_{allowed j}(e^{s_ij}-1) v_j + vtotal
//   den_i = sum_{allowed j}(e^{s_ij}-1) + S
// Only blocks jb <= bi are visited (~half the work).
// ---------------------------------------------------------------------------
__global__ __launch_bounds__(256) void attn_kernel(
    const float* __restrict__ q, const float* __restrict__ k,
    const float* __restrict__ v, const float* __restrict__ vtotal,
    float* __restrict__ ctx)
{
  __shared__ float qs[32 * 68];   // row stride 68 breaks stride-64 bank aliasing
  __shared__ float ks[32 * 68];
  __shared__ float vs[32 * 68];
  __shared__ float es[32 * 33];   // exp(score)-1
  const int tid = threadIdx.x;
  const int bi  = (kNBlk - 1) - blockIdx.x;  // heavy blocks dispatched first
  const int h   = blockIdx.y;
  const int b   = blockIdx.z;
  const int bh  = b * kNH + h;

  // load Q tile (contiguous 32x64 chunk), pre-scaled by 1/sqrt(64)
  const float* qbase = q + ((size_t)bh * kS + (size_t)bi * kWin) * kHD;
#pragma unroll
  for (int r = 0; r < 2; ++r) {
    const int t   = tid + r * 256;
    const int row = t >> 4;
    const int c4  = (t & 15) << 2;
    const float4 qv = *(const float4*)(qbase + row * kHD + c4);
    qs[row * 68 + c4 + 0] = qv.x * 0.125f;
    qs[row * 68 + c4 + 1] = qv.y * 0.125f;
    qs[row * 68 + c4 + 2] = qv.z * 0.125f;
    qs[row * 68 + c4 + 3] = qv.w * 0.125f;
  }

  float ctxacc[8] = {0.f, 0.f, 0.f, 0.f, 0.f, 0.f, 0.f, 0.f};
  float denom = 0.f;
  const int qi = tid >> 3;         // accum phase: query row 0..31
  const int dg = (tid & 7) << 3;   // accum phase: dim group (8 dims)
  const int qh = tid >> 4;         // score phase: rows qh, qh+16
  const int jh = tid & 15;         // score phase: cols jh, jh+16

  for (int jb = 0; jb <= bi; ++jb) {
    __syncthreads();  // prev iteration's es/vs reads done before overwrite
    const float* kb = k + ((size_t)bh * kS + (size_t)jb * kWin) * kHD;
    const float* vb = v + ((size_t)bh * kS + (size_t)jb * kWin) * kHD;
#pragma unroll
    for (int r = 0; r < 2; ++r) {
      const int t   = tid + r * 256;
      const int row = t >> 4;
      const int c4  = (t & 15) << 2;
      *(float4*)&ks[row * 68 + c4] = *(const float4*)(kb + row * kHD + c4);
      *(float4*)&vs[row * 68 + c4] = *(const float4*)(vb + row * kHD + c4);
    }
    __syncthreads();

    // scores: 2x2 microtile per thread
    float s00 = 0.f, s01 = 0.f, s10 = 0.f, s11 = 0.f;
#pragma unroll
    for (int k4 = 0; k4 < 16; ++k4) {
      const float4 q0  = *(const float4*)&qs[qh * 68 + k4 * 4];
      const float4 q1  = *(const float4*)&qs[(qh + 16) * 68 + k4 * 4];
      const float4 k0v = *(const float4*)&ks[jh * 68 + k4 * 4];
      const float4 k1v = *(const float4*)&ks[(jh + 16) * 68 + k4 * 4];
      s00 = fmaf(q0.x, k0v.x, fmaf(q0.y, k0v.y, fmaf(q0.z, k0v.z, fmaf(q0.w, k0v.w, s00))));
      s01 = fmaf(q0.x, k1v.x, fmaf(q0.y, k1v.y, fmaf(q0.z, k1v.z, fmaf(q0.w, k1v.w, s01))));
      s10 = fmaf(q1.x, k0v.x, fmaf(q1.y, k0v.y, fmaf(q1.z, k0v.z, fmaf(q1.w, k0v.w, s10))));
      s11 = fmaf(q1.x, k1v.x, fmaf(q1.y, k1v.y, fmaf(q1.z, k1v.z, fmaf(q1.w, k1v.w, s11))));
    }
    es[qh * 33 + jh]             = __expf(s00) - 1.f;
    es[qh * 33 + jh + 16]        = __expf(s01) - 1.f;
    es[(qh + 16) * 33 + jh]      = __expf(s10) - 1.f;
    es[(qh + 16) * 33 + jh + 16] = __expf(s11) - 1.f;
    __syncthreads();

    // accumulate (E-1) @ V and denom
#pragma unroll 8
    for (int j = 0; j < 32; ++j) {
      const float e = es[qi * 33 + j];
      const float4 v0 = *(const float4*)&vs[j * 68 + dg];
      const float4 v1 = *(const float4*)&vs[j * 68 + dg + 4];
      ctxacc[0] = fmaf(e, v0.x, ctxacc[0]);
      ctxacc[1] = fmaf(e, v0.y, ctxacc[1]);
      ctxacc[2] = fmaf(e, v0.z, ctxacc[2]);
      ctxacc[3] = fmaf(e, v0.w, ctxacc[3]);
      ctxacc[4] = fmaf(e, v1.x, ctxacc[4]);
      ctxacc[5] = fmaf(e, v1.y, ctxacc[5]);
      ctxacc[6] = fmaf(e, v1.z, ctxacc[6]);
      ctxacc[7] = fmaf(e, v1.w, ctxacc[7]);
      denom += e;
    }
  }

  // finalize: add total-V (covers the masked-as-zero region), divide, store
  const float* vt = vtotal + bh * kHD;
  const float4 vt0 = *(const float4*)(vt + dg);
  const float4 vt1 = *(const float4*)(vt + dg + 4);
  const float inv = 1.f / (denom + (float)kS);
  float4 o0, o1;
  o0.x = (ctxacc[0] + vt0.x) * inv;
  o0.y = (ctxacc[1] + vt0.y) * inv;
  o0.z = (ctxacc[2] + vt0.z) * inv;
  o0.w = (ctxacc[3] + vt0.w) * inv;
  o1.x = (ctxacc[4] + vt1.x) * inv;
  o1.y = (ctxacc[5] + vt1.y) * inv;
  o1.z = (ctxacc[6] + vt1.z) * inv;
  o1.w = (ctxacc[7] + vt1.w) * inv;
  float* dst = ctx + ((size_t)b * kS + (size_t)bi * kWin + qi) * kH + h * kHD + dg;
  *(float4*)dst = o0;
  *(float4*)(dst + 4) = o1;
}

}  // namespace

extern "C" void kernel_launch(void* const* d_in, const int* in_sizes, int n_in,
                              void* d_out, int out_size, void* d_ws, size_t ws_size,
                              hipStream_t stream) {
  const float* hs = (const float*)d_in[0];
  const float* Wq = (const float*)d_in[1];
  const float* bq = (const float*)d_in[2];
  const float* Wk = (const float*)d_in[3];
  const float* bk = (const float*)d_in[4];
  const float* Wv = (const float*)d_in[5];
  const float* bv = (const float*)d_in[6];
  const float* Wo = (const float*)d_in[7];
  const float* bo = (const float*)d_in[8];
  float* out = (float*)d_out;

  float* ws = (float*)d_ws;
  const size_t n_qkv = (size_t)kB * kNH * kS * kHD;  // 4,194,304 floats
  float* q    = ws;
  float* k    = ws + n_qkv;
  float* v    = ws + 2 * n_qkv;
  float* ctx  = ws + 3 * n_qkv;
  float* vtot = ws + 4 * n_qkv;   // + 2048 floats; total ~67 MB of ws

  const int M = kB * kS;  // 4096
  const dim3 gblk(kH / BN, M / BM);  // (8, 32)

  gemm_nt<<<gblk, 256, 0, stream>>>(hs, Wq, bq, q, M, kH, kH, 1);
  gemm_nt<<<gblk, 256, 0, stream>>>(hs, Wk, bk, k, M, kH, kH, 1);
  gemm_nt<<<gblk, 256, 0, stream>>>(hs, Wv, bv, v, M, kH, kH, 1);
  vsum_kernel<<<kB * kNH, 256, 0, stream>>>(v, vtot);
  attn_kernel<<<dim3(kNBlk, kNH, kB), 256, 0, stream>>>(q, k, v, vtot, ctx);
  gemm_nt<<<gblk, 256, 0, stream>>>(ctx, Wo, bo, out, M, kH, kH, 0);
}

// Round 2
// 681.517 us; speedup vs baseline: 1.7497x; 1.7497x over previous
//
#include <hip/hip_runtime.h>
#include <cstdint>

namespace {

constexpr int kS   = 2048;
constexpr int kNH  = 16;
constexpr int kHD  = 64;
constexpr int kH   = 1024;
constexpr int kB   = 2;
constexpr int kWin = 32;
constexpr int kNBlk = kS / kWin;  // 64

typedef __attribute__((ext_vector_type(8))) short short8v;          // 8 x bf16
typedef __attribute__((ext_vector_type(4))) float f32x4;            // MFMA C/D
typedef __attribute__((ext_vector_type(4))) unsigned short u16x4;   // 8B bf16 store

static __device__ __forceinline__ unsigned short f2bf(float f) {
  // round-to-nearest-even fp32 -> bf16 (inputs are finite)
  unsigned int u = __float_as_uint(f);
  return (unsigned short)((u + 0x7fffu + ((u >> 16) & 1u)) >> 16);
}

// ---------------------------------------------------------------------------
// GEMM:  C = A @ W^T + bias
//   mode 0: C fp32 [M,N] row-major
//   mode 1: C fp32 scattered to [B, NH, S, HD]
//   mode 2: C bf16 scattered to [B, NH, S, HD]
// ---------------------------------------------------------------------------
constexpr int BM = 128, BN = 128, BK = 32;

__global__ __launch_bounds__(256) void gemm_nt(
    const float* __restrict__ A, const float* __restrict__ W,
    const float* __restrict__ bias, void* __restrict__ Cv,
    int M, int N, int K, int mode)
{
  __shared__ float As[BK][BM + 4];
  __shared__ float Ws[BK][BN + 4];
  float* C = (float*)Cv;
  unsigned short* C16 = (unsigned short*)Cv;
  const int tid = threadIdx.x;
  const int bm = blockIdx.y * BM;
  const int bn = blockIdx.x * BN;
  const int tx = tid & 15;
  const int ty = tid >> 4;

  float acc[8][8];
#pragma unroll
  for (int i = 0; i < 8; ++i)
#pragma unroll
    for (int j = 0; j < 8; ++j) acc[i][j] = 0.f;

  const int lrow = tid >> 3;
  const int lk   = (tid & 7) << 2;

  for (int k0 = 0; k0 < K; k0 += BK) {
#pragma unroll
    for (int r = 0; r < 4; ++r) {
      const int row = lrow + r * 32;
      const float4 av = *(const float4*)(A + (size_t)(bm + row) * K + (k0 + lk));
      As[lk + 0][row] = av.x;
      As[lk + 1][row] = av.y;
      As[lk + 2][row] = av.z;
      As[lk + 3][row] = av.w;
      const float4 wv = *(const float4*)(W + (size_t)(bn + row) * K + (k0 + lk));
      Ws[lk + 0][row] = wv.x;
      Ws[lk + 1][row] = wv.y;
      Ws[lk + 2][row] = wv.z;
      Ws[lk + 3][row] = wv.w;
    }
    __syncthreads();
#pragma unroll
    for (int k = 0; k < BK; ++k) {
      const float4 a0 = *(const float4*)&As[k][ty * 4];
      const float4 a1 = *(const float4*)&As[k][64 + ty * 4];
      const float4 b0 = *(const float4*)&Ws[k][tx * 4];
      const float4 b1 = *(const float4*)&Ws[k][64 + tx * 4];
      const float a[8] = {a0.x, a0.y, a0.z, a0.w, a1.x, a1.y, a1.z, a1.w};
      const float b[8] = {b0.x, b0.y, b0.z, b0.w, b1.x, b1.y, b1.z, b1.w};
#pragma unroll
      for (int i = 0; i < 8; ++i)
#pragma unroll
        for (int j = 0; j < 8; ++j) acc[i][j] = fmaf(a[i], b[j], acc[i][j]);
    }
    __syncthreads();
  }

#pragma unroll
  for (int jg = 0; jg < 2; ++jg) {
    const int col = bn + jg * 64 + tx * 4;
    const float4 bv = *(const float4*)(bias + col);
#pragma unroll
    for (int i = 0; i < 8; ++i) {
      const int row = bm + (i >> 2) * 64 + ty * 4 + (i & 3);
      float4 o;
      o.x = acc[i][jg * 4 + 0] + bv.x;
      o.y = acc[i][jg * 4 + 1] + bv.y;
      o.z = acc[i][jg * 4 + 2] + bv.z;
      o.w = acc[i][jg * 4 + 3] + bv.w;
      if (mode == 0) {
        *(float4*)(C + (size_t)row * N + col) = o;
      } else {
        const int b = row >> 11;
        const int s = row & 2047;
        const int h = col >> 6;
        const int d = col & 63;
        const size_t addr = (((size_t)(b * kNH + h) * kS + s) * kHD + d);
        if (mode == 1) {
          *(float4*)(C + addr) = o;
        } else {
          u16x4 pk;
          pk[0] = f2bf(o.x); pk[1] = f2bf(o.y); pk[2] = f2bf(o.z); pk[3] = f2bf(o.w);
          *(u16x4*)(C16 + addr) = pk;
        }
      }
    }
  }
}

// ---------------------------------------------------------------------------
// vtotal[bh][d] = sum_s v[bh][s][d]
// ---------------------------------------------------------------------------
__global__ __launch_bounds__(256) void vsum_kernel(const float* __restrict__ v,
                                                   float* __restrict__ vtotal) {
  __shared__ float red[4][64];
  const int bh = blockIdx.x;
  const int d  = threadIdx.x & 63;
  const int c  = threadIdx.x >> 6;
  const float* base = v + (size_t)bh * kS * kHD + (size_t)c * 512 * kHD + d;
  float s = 0.f;
#pragma unroll 8
  for (int i = 0; i < 512; ++i) s += base[(size_t)i * kHD];
  red[c][d] = s;
  __syncthreads();
  if (c == 0) {
    vtotal[bh * kHD + d] = red[0][d] + red[1][d] + red[2][d] + red[3][d];
  }
}

// ---------------------------------------------------------------------------
// V fp32 [bh][s][d]  ->  Vt bf16 [bh][d][s]   (64x64 LDS tiles)
// ---------------------------------------------------------------------------
__global__ __launch_bounds__(256) void transpose_v(const float* __restrict__ v,
                                                   unsigned short* __restrict__ vt) {
  __shared__ unsigned short tile[64][68];  // stride 68 u16 = 136B (8B aligned rows)
  const int bh = blockIdx.y;
  const int st = blockIdx.x;
  const int t = threadIdx.x;
  const float* src = v + ((size_t)bh * kS + (size_t)st * 64) * kHD;
#pragma unroll
  for (int i = 0; i < 4; ++i) {
    const int s = (t >> 4) + 16 * i;
    const int d = (t & 15) * 4;
    const float4 f = *(const float4*)(src + s * kHD + d);
    tile[d + 0][s] = f2bf(f.x);
    tile[d + 1][s] = f2bf(f.y);
    tile[d + 2][s] = f2bf(f.z);
    tile[d + 3][s] = f2bf(f.w);
  }
  __syncthreads();
  unsigned short* dst = vt + ((size_t)bh * kHD + (t >> 2)) * kS + st * 64 + (t & 3) * 16;
  const unsigned short* row = &tile[t >> 2][(t & 3) * 16];
#pragma unroll
  for (int c = 0; c < 4; ++c) {
    *(u16x4*)(dst + c * 4) = *(const u16x4*)(row + c * 4);
  }
}

// ---------------------------------------------------------------------------
// MFMA attention. One workgroup (4 waves) per (bh, qblock bi); wave w handles
// jb = w, w+4, ...  Scores computed as S^T = K·Q^T so exp(S)-1 exits in a
// layout that packs row-contiguously into LDS (XOR-swizzled) and reads back
// as b128 A-fragments for the E·V MFMA. Identity used:
//   ctx_i = (sum_{allowed j}(e^{s_ij}-1) v_j + vtotal) / (sum(e-1) + S)
// ---------------------------------------------------------------------------
__global__ __launch_bounds__(256) void attn_mfma(
    const unsigned short* __restrict__ qb, const unsigned short* __restrict__ kb,
    const unsigned short* __restrict__ vtb, const float* __restrict__ vtotal,
    float* __restrict__ ctx)
{
  __shared__ union SM {
    unsigned short es[4][32 * 32];                    // per-wave E (bf16), 8KB
    struct { float part[2][2048]; float den[4][32]; } m;  // merge phase, 16.5KB
  } sm;

  const int tid  = threadIdx.x;
  const int wave = tid >> 6;
  const int lane = tid & 63;
  const int q16  = lane & 15;
  const int quad = lane >> 4;
  const int bh = blockIdx.x & 31;          // bh fastest -> same bh same XCD (%8)
  const int bi = (kNBlk - 1) - (blockIdx.x >> 5);  // heavy q-blocks first
  const int b  = bh >> 4, h = bh & 15;

  const unsigned short* Qb  = qb  + ((size_t)bh * kS + (size_t)bi * kWin) * kHD;
  const unsigned short* Kb  = kb  + (size_t)bh * kS * kHD;
  const unsigned short* Vtb = vtb + (size_t)bh * kHD * kS;

  // Q fragments (B-operand of S^T): lane: n=query qt*16+q16, k=dim ks*32+quad*8+j
  short8v qf[2][2];
#pragma unroll
  for (int qt = 0; qt < 2; ++qt)
#pragma unroll
    for (int ks = 0; ks < 2; ++ks)
      qf[qt][ks] = *(const short8v*)(Qb + (qt * 16 + q16) * kHD + ks * 32 + quad * 8);

  const f32x4 zero = {0.f, 0.f, 0.f, 0.f};
  f32x4 acc[2][4];
#pragma unroll
  for (int mt = 0; mt < 2; ++mt)
#pragma unroll
    for (int nt = 0; nt < 4; ++nt) acc[mt][nt] = zero;
  float dAcc0 = 0.f, dAcc1 = 0.f;

  unsigned short* esw = sm.es[wave];
  const int swz = (q16 >> 2) & 3;   // XOR swizzle on 16B granules of Es rows

  for (int jb = wave; jb <= bi; jb += 4) {
    const unsigned short* Kj = Kb + (size_t)jb * kWin * kHD;
    // K fragments (A-operand): lane: m=key kt*16+q16, k=dim ks*32+quad*8+j
    short8v kf[2][2];
#pragma unroll
    for (int kt = 0; kt < 2; ++kt)
#pragma unroll
      for (int ks = 0; ks < 2; ++ks)
        kf[kt][ks] = *(const short8v*)(Kj + (kt * 16 + q16) * kHD + ks * 32 + quad * 8);

    // S^T tiles: C[key=quad*4+r (+16kt)][query=q16 (+16qt)]
    f32x4 st[2][2];
#pragma unroll
    for (int kt = 0; kt < 2; ++kt)
#pragma unroll
      for (int qt = 0; qt < 2; ++qt) {
        f32x4 c = zero;
        c = __builtin_amdgcn_mfma_f32_16x16x32_bf16(kf[kt][0], qf[qt][0], c, 0, 0, 0);
        c = __builtin_amdgcn_mfma_f32_16x16x32_bf16(kf[kt][1], qf[qt][1], c, 0, 0, 0);
        st[kt][qt] = c;
      }

    // e = exp(s/8)-1 ; accumulate denom ; pack into Es[q][key^swz-granule]
#pragma unroll
    for (int kt = 0; kt < 2; ++kt) {
      const int g = kt * 2 + (quad >> 1);           // key granule (key>>3)
      const int col = ((g ^ swz) * 8) + (quad & 1) * 4;
#pragma unroll
      for (int qt = 0; qt < 2; ++qt) {
        const float e0 = __expf(st[kt][qt][0] * 0.125f) - 1.f;
        const float e1 = __expf(st[kt][qt][1] * 0.125f) - 1.f;
        const float e2 = __expf(st[kt][qt][2] * 0.125f) - 1.f;
        const float e3 = __expf(st[kt][qt][3] * 0.125f) - 1.f;
        if (qt == 0) dAcc0 += (e0 + e1) + (e2 + e3);
        else         dAcc1 += (e0 + e1) + (e2 + e3);
        const unsigned int w0 = (unsigned int)f2bf(e0) | ((unsigned int)f2bf(e1) << 16);
        const unsigned int w1 = (unsigned int)f2bf(e2) | ((unsigned int)f2bf(e3) << 16);
        const int q = qt * 16 + q16;
        *(unsigned int*)(esw + q * 32 + col)     = w0;
        *(unsigned int*)(esw + q * 32 + col + 2) = w1;
      }
    }

    // E A-fragments: lane m=q16(+16mt), k=key quad*8+j  (granule==quad)
    const short8v af0 = *(const short8v*)(esw + (q16)      * 32 + (quad ^ swz) * 8);
    const short8v af1 = *(const short8v*)(esw + (16 + q16) * 32 + (quad ^ swz) * 8);

    // E·V: B-operand from Vt: lane n=dim nt*16+q16, k=key quad*8+j
#pragma unroll
    for (int nt = 0; nt < 4; ++nt) {
      const short8v vf = *(const short8v*)(Vtb + (size_t)(nt * 16 + q16) * kS +
                                           jb * kWin + quad * 8);
      acc[0][nt] = __builtin_amdgcn_mfma_f32_16x16x32_bf16(af0, vf, acc[0][nt], 0, 0, 0);
      acc[1][nt] = __builtin_amdgcn_mfma_f32_16x16x32_bf16(af1, vf, acc[1][nt], 0, 0, 0);
    }
  }

  // reduce denom over quads (keys) -> every lane holds full sum for its query
  dAcc0 += __shfl_xor(dAcc0, 16); dAcc0 += __shfl_xor(dAcc0, 32);
  dAcc1 += __shfl_xor(dAcc1, 16); dAcc1 += __shfl_xor(dAcc1, 32);

  __syncthreads();  // all waves done with es before aliasing as part/den
  if (quad == 0) {
    sm.m.den[wave][q16]      = dAcc0;
    sm.m.den[wave][16 + q16] = dAcc1;
  }
  if (wave < 2) {
    float* p = sm.m.part[wave];
#pragma unroll
    for (int mt = 0; mt < 2; ++mt)
#pragma unroll
      for (int nt = 0; nt < 4; ++nt)
#pragma unroll
        for (int r = 0; r < 4; ++r)
          p[((mt * 4 + nt) * 4 + r) * 64 + lane] = acc[mt][nt][r];
  }
  __syncthreads();
  if (wave >= 2) {
    float* p = sm.m.part[wave - 2];
#pragma unroll
    for (int mt = 0; mt < 2; ++mt)
#pragma unroll
      for (int nt = 0; nt < 4; ++nt)
#pragma unroll
        for (int r = 0; r < 4; ++r)
          p[((mt * 4 + nt) * 4 + r) * 64 + lane] += acc[mt][nt][r];
  }
  __syncthreads();

  // finalize: wave w owns dim-tile nt==w
  {
    const int nt = wave;
    const int dim = nt * 16 + q16;
    const float vt = vtotal[bh * kHD + dim];
    float* outb = ctx + ((size_t)b * kS + (size_t)bi * kWin) * kH + h * kHD;
#pragma unroll
    for (int mt = 0; mt < 2; ++mt) {
#pragma unroll
      for (int r = 0; r < 4; ++r) {
        const int idx = ((mt * 4 + nt) * 4 + r) * 64 + lane;
        const int qrow = mt * 16 + quad * 4 + r;
        const float den = sm.m.den[0][qrow] + sm.m.den[1][qrow] +
                          sm.m.den[2][qrow] + sm.m.den[3][qrow] + (float)kS;
        outb[(size_t)qrow * kH + dim] = (sm.m.part[0][idx] + sm.m.part[1][idx] + vt) / den;
      }
    }
  }
}

}  // namespace

extern "C" void kernel_launch(void* const* d_in, const int* in_sizes, int n_in,
                              void* d_out, int out_size, void* d_ws, size_t ws_size,
                              hipStream_t stream) {
  const float* hs = (const float*)d_in[0];
  const float* Wq = (const float*)d_in[1];
  const float* bq = (const float*)d_in[2];
  const float* Wk = (const float*)d_in[3];
  const float* bk = (const float*)d_in[4];
  const float* Wv = (const float*)d_in[5];
  const float* bv = (const float*)d_in[6];
  const float* Wo = (const float*)d_in[7];
  const float* bo = (const float*)d_in[8];
  float* out = (float*)d_out;

  char* wsb = (char*)d_ws;
  unsigned short* qbuf  = (unsigned short*)(wsb);                  //  8 MB bf16 [bh][s][d]
  unsigned short* kbuf  = (unsigned short*)(wsb + (8u << 20));     //  8 MB bf16 [bh][s][d]
  float*          vbuf  = (float*)         (wsb + (16u << 20));    // 16 MB fp32 [bh][s][d]
  unsigned short* vtbuf = (unsigned short*)(wsb + (32u << 20));    //  8 MB bf16 [bh][d][s]
  float*          ctxb  = (float*)         (wsb + (40u << 20));    // 16 MB fp32 [M][H]
  float*          vtot  = (float*)         (wsb + (56u << 20));    //  8 KB

  const int M = kB * kS;  // 4096
  const dim3 gblk(kH / BN, M / BM);  // (8, 32)

  gemm_nt<<<gblk, 256, 0, stream>>>(hs, Wq, bq, qbuf, M, kH, kH, 2);
  gemm_nt<<<gblk, 256, 0, stream>>>(hs, Wk, bk, kbuf, M, kH, kH, 2);
  gemm_nt<<<gblk, 256, 0, stream>>>(hs, Wv, bv, vbuf, M, kH, kH, 1);
  vsum_kernel<<<kB * kNH, 256, 0, stream>>>(vbuf, vtot);
  transpose_v<<<dim3(kS / 64, kB * kNH), 256, 0, stream>>>(vbuf, vtbuf);
  attn_mfma<<<kNBlk * kB * kNH, 256, 0, stream>>>(qbuf, kbuf, vtbuf, vtot, ctxb);
  gemm_nt<<<gblk, 256, 0, stream>>>(ctxb, Wo, bo, out, M, kH, kH, 0);
}

// Round 3
// 278.909 us; speedup vs baseline: 4.2755x; 2.4435x over previous
//
#include <hip/hip_runtime.h>
#include <cstdint>

namespace {

constexpr int kS   = 2048;
constexpr int kNH  = 16;
constexpr int kHD  = 64;
constexpr int kH   = 1024;
constexpr int kB   = 2;
constexpr int kWin = 32;
constexpr int kNBlk = kS / kWin;  // 64

typedef __attribute__((ext_vector_type(8))) short short8v;          // 8 x bf16
typedef __attribute__((ext_vector_type(4))) float f32x4;            // MFMA C/D
typedef __attribute__((ext_vector_type(4))) unsigned short u16x4;
typedef __attribute__((ext_vector_type(8))) unsigned short u16x8;

static __device__ __forceinline__ unsigned short f2bf(float f) {
  unsigned int u = __float_as_uint(f);
  return (unsigned short)((u + 0x7fffu + ((u >> 16) & 1u)) >> 16);
}
static __device__ __forceinline__ float bf2f(unsigned short b) {
  return __uint_as_float((unsigned int)b << 16);
}
static __device__ __forceinline__ void async16(const void* g, void* l) {
  __builtin_amdgcn_global_load_lds((__attribute__((address_space(1))) void*)(g),
                                   (__attribute__((address_space(3))) void*)(l),
                                   16, 0, 0);
}

// ---------------------------------------------------------------------------
// fp32 -> bf16 for hs (4M) and the four 1M weights, one dispatch.
// out layout: [hs 4M | Wq 1M | Wk 1M | Wv 1M | Wo 1M]
// ---------------------------------------------------------------------------
__global__ __launch_bounds__(256) void cvt_bf16(
    const float* __restrict__ hs, const float* __restrict__ Wq,
    const float* __restrict__ Wk, const float* __restrict__ Wv,
    const float* __restrict__ Wo, unsigned short* __restrict__ out)
{
  const size_t idx = ((size_t)blockIdx.x * 256 + threadIdx.x) * 8;
  const int seg = (int)(idx >> 20);
  const size_t off = idx & ((1u << 20) - 1);
  const float* src;
  if (seg < 4)       src = hs + idx;
  else if (seg == 4) src = Wq + off;
  else if (seg == 5) src = Wk + off;
  else if (seg == 6) src = Wv + off;
  else               src = Wo + off;
  const float4 f0 = *(const float4*)(src);
  const float4 f1 = *(const float4*)(src + 4);
  u16x8 pk;
  pk[0] = f2bf(f0.x); pk[1] = f2bf(f0.y); pk[2] = f2bf(f0.z); pk[3] = f2bf(f0.w);
  pk[4] = f2bf(f1.x); pk[5] = f2bf(f1.y); pk[6] = f2bf(f1.z); pk[7] = f2bf(f1.w);
  *(u16x8*)(out + idx) = pk;
}

// ---------------------------------------------------------------------------
// bf16 MFMA GEMM:  C = A @ W^T + bias.  A [M,K] bf16, W [N,K] bf16.
// 128x128x32 tile, 4 waves (2x2), wave tile 64x64 as 4x4 of 16x16x32.
// Staging via global_load_lds(16B); 16B chunks XOR-swizzled: LDS chunk
// c' = c ^ ((row>>1)&3) so both DMA writes and ds_read_b128 fragment reads
// are uniformly spread across banks.
//   mode 0: C fp32 [M,N]
//   mode 2: C bf16 scattered to [B,NH,S,HD]       (Q, K)
//   mode 3: C bf16 scattered transposed [B,NH,HD,S] (V -> Vt, free transpose)
// ---------------------------------------------------------------------------
__global__ __launch_bounds__(256) void gemm_mfma(
    const unsigned short* __restrict__ A, const unsigned short* __restrict__ W,
    const float* __restrict__ bias, void* __restrict__ Cv,
    int M, int N, int K, int mode)
{
  __shared__ unsigned short As[128 * 32];  // 8 KB
  __shared__ unsigned short Ws[128 * 32];  // 8 KB
  const int tid  = threadIdx.x;
  const int wave = tid >> 6, lane = tid & 63;
  const int q16  = lane & 15, quad = lane >> 4;
  const int wm   = wave & 1,  wn   = wave >> 1;
  const int bm = blockIdx.y * 128, bn = blockIdx.x * 128;

  // staging source addresses (lane-constant chunk swizzle)
  const int lrow   = lane >> 2;                       // row within 16-row group
  const int lchunk = (lane & 3) ^ ((lane >> 3) & 3);  // global k-chunk to fetch
  const unsigned short* gA0 = A + (size_t)(bm + wave * 32 + lrow) * K + lchunk * 8;
  const unsigned short* gA1 = gA0 + (size_t)16 * K;
  const unsigned short* gW0 = W + (size_t)(bn + wave * 32 + lrow) * K + lchunk * 8;
  const unsigned short* gW1 = gW0 + (size_t)16 * K;
  unsigned short* lA0 = As + (wave * 32) * 32;
  unsigned short* lA1 = lA0 + 16 * 32;
  unsigned short* lW0 = Ws + (wave * 32) * 32;
  unsigned short* lW1 = lW0 + 16 * 32;

  // fragment read bases (lane-constant): row = wm*64 + mt*16 + q16, chunk=quad
  const int swz = quad ^ ((q16 >> 1) & 3);
  const unsigned short* fA = As + (wm * 64 + q16) * 32 + swz * 8;
  const unsigned short* fB = Ws + (wn * 64 + q16) * 32 + swz * 8;

  const f32x4 zero = {0.f, 0.f, 0.f, 0.f};
  f32x4 acc[4][4];
#pragma unroll
  for (int i = 0; i < 4; ++i)
#pragma unroll
    for (int j = 0; j < 4; ++j) acc[i][j] = zero;

  for (int k0 = 0; k0 < K; k0 += 32) {
    __syncthreads();  // prior ds_reads complete before overwrite
    async16(gA0, lA0);
    async16(gA1, lA1);
    async16(gW0, lW0);
    async16(gW1, lW1);
    gA0 += 32; gA1 += 32; gW0 += 32; gW1 += 32;
    __syncthreads();  // staging visible

    short8v a[4], b[4];
#pragma unroll
    for (int t = 0; t < 4; ++t) {
      a[t] = *(const short8v*)(fA + t * 16 * 32);
      b[t] = *(const short8v*)(fB + t * 16 * 32);
    }
#pragma unroll
    for (int mt = 0; mt < 4; ++mt)
#pragma unroll
      for (int nt = 0; nt < 4; ++nt)
        acc[mt][nt] = __builtin_amdgcn_mfma_f32_16x16x32_bf16(a[mt], b[nt], acc[mt][nt], 0, 0, 0);
  }

  // epilogue. C/D layout: col = lane&15 (n), row = quad*4 + reg (m).
  float* Cf = (float*)Cv;
  unsigned short* C16 = (unsigned short*)Cv;
#pragma unroll
  for (int nt = 0; nt < 4; ++nt) {
    const int col = bn + wn * 64 + nt * 16 + q16;
    const float bv = bias[col];
#pragma unroll
    for (int mt = 0; mt < 4; ++mt) {
      const int row0 = bm + wm * 64 + mt * 16 + quad * 4;
      const f32x4 av = acc[mt][nt];
      if (mode == 0) {
#pragma unroll
        for (int r = 0; r < 4; ++r)
          Cf[(size_t)(row0 + r) * N + col] = av[r] + bv;
      } else {
        const int b = row0 >> 11, s0 = row0 & 2047;
        const int h = col >> 6,   d  = col & 63;
        if (mode == 2) {
          unsigned short* base = C16 + (((size_t)(b * kNH + h) * kS + s0) * kHD + d);
#pragma unroll
          for (int r = 0; r < 4; ++r) base[(size_t)r * kHD] = f2bf(av[r] + bv);
        } else {  // mode 3: Vt[bh][d][s], 4 consecutive s -> one 8B store
          u16x4 pk;
          pk[0] = f2bf(av[0] + bv); pk[1] = f2bf(av[1] + bv);
          pk[2] = f2bf(av[2] + bv); pk[3] = f2bf(av[3] + bv);
          *(u16x4*)(C16 + ((size_t)(b * kNH + h) * kHD + d) * kS + s0) = pk;
        }
      }
    }
  }
}

// ---------------------------------------------------------------------------
// vtotal[bh][d] = sum_s Vt[bh][d][s]   (fp32 accumulation over bf16)
// ---------------------------------------------------------------------------
__global__ __launch_bounds__(256) void vsum_t(const unsigned short* __restrict__ vt,
                                              float* __restrict__ vtotal) {
  __shared__ float red[256];
  const int bh = blockIdx.x;
  const int d = threadIdx.x >> 2, part = threadIdx.x & 3;
  const unsigned short* base = vt + ((size_t)bh * kHD + d) * kS + part * 512;
  float s = 0.f;
#pragma unroll 4
  for (int i = 0; i < 64; ++i) {
    const u16x8 v = *(const u16x8*)(base + i * 8);
#pragma unroll
    for (int j = 0; j < 8; ++j) s += bf2f(v[j]);
  }
  red[threadIdx.x] = s;
  __syncthreads();
  if (part == 0)
    vtotal[bh * kHD + d] = red[d * 4] + red[d * 4 + 1] + red[d * 4 + 2] + red[d * 4 + 3];
}

// ---------------------------------------------------------------------------
// MFMA attention (round-2 structure), ctx emitted as bf16 [M][H].
//   ctx_i = (sum_{allowed j}(e^{s_ij}-1) v_j + vtotal) / (sum(e-1) + S)
// ---------------------------------------------------------------------------
__global__ __launch_bounds__(256) void attn_mfma(
    const unsigned short* __restrict__ qb, const unsigned short* __restrict__ kb,
    const unsigned short* __restrict__ vtb, const float* __restrict__ vtotal,
    unsigned short* __restrict__ ctx)
{
  __shared__ union SM {
    unsigned short es[4][32 * 32];
    struct { float part[2][2048]; float den[4][32]; } m;
  } sm;

  const int tid  = threadIdx.x;
  const int wave = tid >> 6;
  const int lane = tid & 63;
  const int q16  = lane & 15;
  const int quad = lane >> 4;
  const int bh = blockIdx.x & 31;
  const int bi = (kNBlk - 1) - (blockIdx.x >> 5);
  const int b  = bh >> 4, h = bh & 15;

  const unsigned short* Qb  = qb  + ((size_t)bh * kS + (size_t)bi * kWin) * kHD;
  const unsigned short* Kb  = kb  + (size_t)bh * kS * kHD;
  const unsigned short* Vtb = vtb + (size_t)bh * kHD * kS;

  short8v qf[2][2];
#pragma unroll
  for (int qt = 0; qt < 2; ++qt)
#pragma unroll
    for (int ks = 0; ks < 2; ++ks)
      qf[qt][ks] = *(const short8v*)(Qb + (qt * 16 + q16) * kHD + ks * 32 + quad * 8);

  const f32x4 zero = {0.f, 0.f, 0.f, 0.f};
  f32x4 acc[2][4];
#pragma unroll
  for (int mt = 0; mt < 2; ++mt)
#pragma unroll
    for (int nt = 0; nt < 4; ++nt) acc[mt][nt] = zero;
  float dAcc0 = 0.f, dAcc1 = 0.f;

  unsigned short* esw = sm.es[wave];
  const int swz = (q16 >> 2) & 3;

  for (int jb = wave; jb <= bi; jb += 4) {
    const unsigned short* Kj = Kb + (size_t)jb * kWin * kHD;
    short8v kf[2][2];
#pragma unroll
    for (int kt = 0; kt < 2; ++kt)
#pragma unroll
      for (int ks = 0; ks < 2; ++ks)
        kf[kt][ks] = *(const short8v*)(Kj + (kt * 16 + q16) * kHD + ks * 32 + quad * 8);

    f32x4 st[2][2];
#pragma unroll
    for (int kt = 0; kt < 2; ++kt)
#pragma unroll
      for (int qt = 0; qt < 2; ++qt) {
        f32x4 c = zero;
        c = __builtin_amdgcn_mfma_f32_16x16x32_bf16(kf[kt][0], qf[qt][0], c, 0, 0, 0);
        c = __builtin_amdgcn_mfma_f32_16x16x32_bf16(kf[kt][1], qf[qt][1], c, 0, 0, 0);
        st[kt][qt] = c;
      }

#pragma unroll
    for (int kt = 0; kt < 2; ++kt) {
      const int g = kt * 2 + (quad >> 1);
      const int col = ((g ^ swz) * 8) + (quad & 1) * 4;
#pragma unroll
      for (int qt = 0; qt < 2; ++qt) {
        const float e0 = __expf(st[kt][qt][0] * 0.125f) - 1.f;
        const float e1 = __expf(st[kt][qt][1] * 0.125f) - 1.f;
        const float e2 = __expf(st[kt][qt][2] * 0.125f) - 1.f;
        const float e3 = __expf(st[kt][qt][3] * 0.125f) - 1.f;
        if (qt == 0) dAcc0 += (e0 + e1) + (e2 + e3);
        else         dAcc1 += (e0 + e1) + (e2 + e3);
        const unsigned int w0 = (unsigned int)f2bf(e0) | ((unsigned int)f2bf(e1) << 16);
        const unsigned int w1 = (unsigned int)f2bf(e2) | ((unsigned int)f2bf(e3) << 16);
        const int q = qt * 16 + q16;
        *(unsigned int*)(esw + q * 32 + col)     = w0;
        *(unsigned int*)(esw + q * 32 + col + 2) = w1;
      }
    }

    const short8v af0 = *(const short8v*)(esw + (q16)      * 32 + (quad ^ swz) * 8);
    const short8v af1 = *(const short8v*)(esw + (16 + q16) * 32 + (quad ^ swz) * 8);

#pragma unroll
    for (int nt = 0; nt < 4; ++nt) {
      const short8v vf = *(const short8v*)(Vtb + (size_t)(nt * 16 + q16) * kS +
                                           jb * kWin + quad * 8);
      acc[0][nt] = __builtin_amdgcn_mfma_f32_16x16x32_bf16(af0, vf, acc[0][nt], 0, 0, 0);
      acc[1][nt] = __builtin_amdgcn_mfma_f32_16x16x32_bf16(af1, vf, acc[1][nt], 0, 0, 0);
    }
  }

  dAcc0 += __shfl_xor(dAcc0, 16); dAcc0 += __shfl_xor(dAcc0, 32);
  dAcc1 += __shfl_xor(dAcc1, 16); dAcc1 += __shfl_xor(dAcc1, 32);

  __syncthreads();
  if (quad == 0) {
    sm.m.den[wave][q16]      = dAcc0;
    sm.m.den[wave][16 + q16] = dAcc1;
  }
  if (wave < 2) {
    float* p = sm.m.part[wave];
#pragma unroll
    for (int mt = 0; mt < 2; ++mt)
#pragma unroll
      for (int nt = 0; nt < 4; ++nt)
#pragma unroll
        for (int r = 0; r < 4; ++r)
          p[((mt * 4 + nt) * 4 + r) * 64 + lane] = acc[mt][nt][r];
  }
  __syncthreads();
  if (wave >= 2) {
    float* p = sm.m.part[wave - 2];
#pragma unroll
    for (int mt = 0; mt < 2; ++mt)
#pragma unroll
      for (int nt = 0; nt < 4; ++nt)
#pragma unroll
        for (int r = 0; r < 4; ++r)
          p[((mt * 4 + nt) * 4 + r) * 64 + lane] += acc[mt][nt][r];
  }
  __syncthreads();

  {
    const int nt = wave;
    const int dim = nt * 16 + q16;
    const float vt = vtotal[bh * kHD + dim];
    unsigned short* outb = ctx + ((size_t)b * kS + (size_t)bi * kWin) * kH + h * kHD;
#pragma unroll
    for (int mt = 0; mt < 2; ++mt) {
#pragma unroll
      for (int r = 0; r < 4; ++r) {
        const int idx = ((mt * 4 + nt) * 4 + r) * 64 + lane;
        const int qrow = mt * 16 + quad * 4 + r;
        const float den = sm.m.den[0][qrow] + sm.m.den[1][qrow] +
                          sm.m.den[2][qrow] + sm.m.den[3][qrow] + (float)kS;
        outb[(size_t)qrow * kH + dim] =
            f2bf((sm.m.part[0][idx] + sm.m.part[1][idx] + vt) / den);
      }
    }
  }
}

}  // namespace

extern "C" void kernel_launch(void* const* d_in, const int* in_sizes, int n_in,
                              void* d_out, int out_size, void* d_ws, size_t ws_size,
                              hipStream_t stream) {
  const float* hs = (const float*)d_in[0];
  const float* Wq = (const float*)d_in[1];
  const float* bq = (const float*)d_in[2];
  const float* Wk = (const float*)d_in[3];
  const float* bk = (const float*)d_in[4];
  const float* Wv = (const float*)d_in[5];
  const float* bv = (const float*)d_in[6];
  const float* Wo = (const float*)d_in[7];
  const float* bo = (const float*)d_in[8];

  char* wsb = (char*)d_ws;
  unsigned short* hsb   = (unsigned short*)(wsb);                 //  8 MB [M][K] bf16
  unsigned short* wqb   = hsb + (4u << 20);                       //  2 MB
  unsigned short* wkb   = hsb + (5u << 20);
  unsigned short* wvb   = hsb + (6u << 20);
  unsigned short* wob   = hsb + (7u << 20);
  unsigned short* qbuf  = (unsigned short*)(wsb + (16u << 20));   //  8 MB [bh][s][d]
  unsigned short* kbuf  = (unsigned short*)(wsb + (24u << 20));   //  8 MB [bh][s][d]
  unsigned short* vtbuf = (unsigned short*)(wsb + (32u << 20));   //  8 MB [bh][d][s]
  unsigned short* ctxb  = (unsigned short*)(wsb + (40u << 20));   //  8 MB [M][H] bf16
  float*          vtot  = (float*)         (wsb + (48u << 20));   //  8 KB

  const int M = kB * kS;  // 4096
  const dim3 gblk(kH / 128, M / 128);  // (8, 32)

  cvt_bf16<<<4096, 256, 0, stream>>>(hs, Wq, Wk, Wv, Wo, hsb);
  gemm_mfma<<<gblk, 256, 0, stream>>>(hsb, wqb, bq, qbuf, M, kH, kH, 2);
  gemm_mfma<<<gblk, 256, 0, stream>>>(hsb, wkb, bk, kbuf, M, kH, kH, 2);
  gemm_mfma<<<gblk, 256, 0, stream>>>(hsb, wvb, bv, vtbuf, M, kH, kH, 3);
  vsum_t<<<kB * kNH, 256, 0, stream>>>(vtbuf, vtot);
  attn_mfma<<<kNBlk * kB * kNH, 256, 0, stream>>>(qbuf, kbuf, vtbuf, vtot, ctxb);
  gemm_mfma<<<gblk, 256, 0, stream>>>(ctxb, wob, bo, d_out, M, kH, kH, 0);
}

// Round 4
// 247.933 us; speedup vs baseline: 4.8097x; 1.1249x over previous
//
#include <hip/hip_runtime.h>
#include <cstdint>

namespace {

constexpr int kS   = 2048;
constexpr int kNH  = 16;
constexpr int kHD  = 64;
constexpr int kH   = 1024;
constexpr int kB   = 2;
constexpr int kWin = 32;
constexpr int kNBlk = kS / kWin;  // 64
// exp(score/sqrt(64)) == exp2(score * log2(e)/8); folded into Q at projection
constexpr float kQScale = 0.18033688011112042f;

typedef __attribute__((ext_vector_type(8))) short short8v;          // 8 x bf16
typedef __attribute__((ext_vector_type(4))) float f32x4;            // MFMA C/D
typedef __attribute__((ext_vector_type(4))) unsigned short u16x4;
typedef __attribute__((ext_vector_type(8))) unsigned short u16x8;

static __device__ __forceinline__ unsigned short f2bf(float f) {
  unsigned int u = __float_as_uint(f);
  return (unsigned short)((u + 0x7fffu + ((u >> 16) & 1u)) >> 16);
}
static __device__ __forceinline__ float bf2f(unsigned short b) {
  return __uint_as_float((unsigned int)b << 16);
}
static __device__ __forceinline__ void async16(const void* g, void* l) {
  __builtin_amdgcn_global_load_lds((__attribute__((address_space(1))) void*)(g),
                                   (__attribute__((address_space(3))) void*)(l),
                                   16, 0, 0);
}

// ---------------------------------------------------------------------------
// fp32 -> bf16 for hs (4M) and the four 1M weights, one dispatch.
// out layout: [hs 4M | Wq 1M | Wk 1M | Wv 1M | Wo 1M]  (Wq..Wv contiguous ->
// the fused QKV GEMM treats them as one [3072][1024] matrix)
// ---------------------------------------------------------------------------
__global__ __launch_bounds__(256) void cvt_bf16(
    const float* __restrict__ hs, const float* __restrict__ Wq,
    const float* __restrict__ Wk, const float* __restrict__ Wv,
    const float* __restrict__ Wo, unsigned short* __restrict__ out)
{
  const size_t idx = ((size_t)blockIdx.x * 256 + threadIdx.x) * 8;
  const int seg = (int)(idx >> 20);
  const size_t off = idx & ((1u << 20) - 1);
  const float* src;
  if (seg < 4)       src = hs + idx;
  else if (seg == 4) src = Wq + off;
  else if (seg == 5) src = Wk + off;
  else if (seg == 6) src = Wv + off;
  else               src = Wo + off;
  const float4 f0 = *(const float4*)(src);
  const float4 f1 = *(const float4*)(src + 4);
  u16x8 pk;
  pk[0] = f2bf(f0.x); pk[1] = f2bf(f0.y); pk[2] = f2bf(f0.z); pk[3] = f2bf(f0.w);
  pk[4] = f2bf(f1.x); pk[5] = f2bf(f1.y); pk[6] = f2bf(f1.z); pk[7] = f2bf(f1.w);
  *(u16x8*)(out + idx) = pk;
}

// ---------------------------------------------------------------------------
// bf16 MFMA GEMM, templated block-M (MT*32 rows) x 128 cols x 32 k-tile.
// 4 waves as 2x2; wave tile (MT*16) x 64 = MT x 4 tiles of 16x16x32.
// Staging via global_load_lds(16B) with 16B-chunk XOR swizzle.
//   EPI 0: C fp32 [M,N] += bias                       (out-GEMM)
//   EPI 1: fused QKV routing: col>>10 selects matrix:
//          0 -> Q bf16 [bh][s][d] scaled by kQScale
//          1 -> K bf16 [bh][s][d]
//          2 -> V bf16 transposed [bh][d][s]
// ---------------------------------------------------------------------------
template <int MT, int EPI>
__global__ __launch_bounds__(256) void gemm_mfma(
    const unsigned short* __restrict__ A, const unsigned short* __restrict__ W,
    const float* __restrict__ b0, const float* __restrict__ b1,
    const float* __restrict__ b2, float* __restrict__ Cf,
    unsigned short* __restrict__ Dq, unsigned short* __restrict__ Dk,
    unsigned short* __restrict__ Dv, int M, int N, int K)
{
  constexpr int BMr = MT * 32;
  constexpr int AG  = MT / 2;           // 16-row staging groups per wave (A)
  __shared__ unsigned short As[BMr * 32];
  __shared__ unsigned short Ws[128 * 32];
  const int tid  = threadIdx.x;
  const int wave = tid >> 6, lane = tid & 63;
  const int q16  = lane & 15, quad = lane >> 4;
  const int wm   = wave & 1,  wn   = wave >> 1;
  const int bm = blockIdx.y * BMr, bn = blockIdx.x * 128;

  const int lrow   = lane >> 2;
  const int lchunk = (lane & 3) ^ ((lane >> 3) & 3);  // content swizzle

  const unsigned short* gA[AG];
  unsigned short* lA[AG];
#pragma unroll
  for (int g = 0; g < AG; ++g) {
    gA[g] = A + (size_t)(bm + wave * 16 * AG + g * 16 + lrow) * K + lchunk * 8;
    lA[g] = As + (wave * 16 * AG + g * 16) * 32;
  }
  const unsigned short* gW0 = W + (size_t)(bn + wave * 32 + lrow) * K + lchunk * 8;
  const unsigned short* gW1 = gW0 + (size_t)16 * K;
  unsigned short* lW0 = Ws + (wave * 32) * 32;
  unsigned short* lW1 = lW0 + 16 * 32;

  const int swz = quad ^ ((q16 >> 1) & 3);
  const unsigned short* fA = As + (wm * (MT * 16) + q16) * 32 + swz * 8;
  const unsigned short* fB = Ws + (wn * 64 + q16) * 32 + swz * 8;

  const f32x4 zero = {0.f, 0.f, 0.f, 0.f};
  f32x4 acc[MT][4];
#pragma unroll
  for (int i = 0; i < MT; ++i)
#pragma unroll
    for (int j = 0; j < 4; ++j) acc[i][j] = zero;

  for (int k0 = 0; k0 < K; k0 += 32) {
    __syncthreads();
#pragma unroll
    for (int g = 0; g < AG; ++g) { async16(gA[g], lA[g]); gA[g] += 32; }
    async16(gW0, lW0);
    async16(gW1, lW1);
    gW0 += 32; gW1 += 32;
    __syncthreads();

    short8v a[MT], b[4];
#pragma unroll
    for (int t = 0; t < MT; ++t) a[t] = *(const short8v*)(fA + t * 16 * 32);
#pragma unroll
    for (int t = 0; t < 4; ++t)  b[t] = *(const short8v*)(fB + t * 16 * 32);
#pragma unroll
    for (int mt = 0; mt < MT; ++mt)
#pragma unroll
      for (int nt = 0; nt < 4; ++nt)
        acc[mt][nt] = __builtin_amdgcn_mfma_f32_16x16x32_bf16(a[mt], b[nt], acc[mt][nt], 0, 0, 0);
  }

  // epilogue. C/D layout: col = lane&15 (n), row = quad*4 + reg (m).
#pragma unroll
  for (int nt = 0; nt < 4; ++nt) {
    const int col = bn + wn * 64 + nt * 16 + q16;
#pragma unroll
    for (int mt = 0; mt < MT; ++mt) {
      const int row0 = bm + wm * (MT * 16) + mt * 16 + quad * 4;
      const f32x4 av = acc[mt][nt];
      if (EPI == 0) {
        const float bv = b0[col];
#pragma unroll
        for (int r = 0; r < 4; ++r)
          Cf[(size_t)(row0 + r) * N + col] = av[r] + bv;
      } else {
        const int mat = col >> 10, c = col & 1023;
        const int b = row0 >> 11, s0 = row0 & 2047;
        const int h = c >> 6, d = c & 63;
        const size_t bhslot = (size_t)(b * kNH + h);
        if (mat == 0) {
          const float bv = b0[c];
          unsigned short* base = Dq + ((bhslot * kS + s0) * kHD + d);
#pragma unroll
          for (int r = 0; r < 4; ++r) base[(size_t)r * kHD] = f2bf((av[r] + bv) * kQScale);
        } else if (mat == 1) {
          const float bv = b1[c];
          unsigned short* base = Dk + ((bhslot * kS + s0) * kHD + d);
#pragma unroll
          for (int r = 0; r < 4; ++r) base[(size_t)r * kHD] = f2bf(av[r] + bv);
        } else {
          const float bv = b2[c];
          u16x4 pk;
          pk[0] = f2bf(av[0] + bv); pk[1] = f2bf(av[1] + bv);
          pk[2] = f2bf(av[2] + bv); pk[3] = f2bf(av[3] + bv);
          *(u16x4*)(Dv + (bhslot * kHD + d) * kS + s0) = pk;
        }
      }
    }
  }
}

// ---------------------------------------------------------------------------
// vtotal[bh][d] = sum_s Vt[bh][d][s]   (fp32 accumulation over bf16)
// ---------------------------------------------------------------------------
__global__ __launch_bounds__(256) void vsum_t(const unsigned short* __restrict__ vt,
                                              float* __restrict__ vtotal) {
  __shared__ float red[256];
  const int bh = blockIdx.x;
  const int d = threadIdx.x >> 2, part = threadIdx.x & 3;
  const unsigned short* base = vt + ((size_t)bh * kHD + d) * kS + part * 512;
  float s = 0.f;
#pragma unroll 4
  for (int i = 0; i < 64; ++i) {
    const u16x8 v = *(const u16x8*)(base + i * 8);
#pragma unroll
    for (int j = 0; j < 8; ++j) s += bf2f(v[j]);
  }
  red[threadIdx.x] = s;
  __syncthreads();
  if (part == 0)
    vtotal[bh * kHD + d] = red[d * 4] + red[d * 4 + 1] + red[d * 4 + 2] + red[d * 4 + 3];
}

// ---------------------------------------------------------------------------
// Attention: ONE WAVE per (bh, qblock). 4 independent waves per block, no
// __syncthreads, per-wave double-buffered E tile in LDS. Q pre-scaled so
// e = exp2(st) - 1.  Identity:
//   ctx_i = (sum_{allowed j}(e_ij) v_j + vtotal) / (sum e_ij + S)
// ---------------------------------------------------------------------------
__global__ __launch_bounds__(256) void attn_wave(
    const unsigned short* __restrict__ qb, const unsigned short* __restrict__ kb,
    const unsigned short* __restrict__ vtb, const float* __restrict__ vtotal,
    unsigned short* __restrict__ ctx)
{
  __shared__ unsigned short es[4][2][1024];  // [wave][parity][32q x 32k], 16KB
  const int tid  = threadIdx.x;
  const int wave = tid >> 6, lane = tid & 63;
  const int q16  = lane & 15, quad = lane >> 4;
  const int unit = blockIdx.x * 4 + wave;
  const int bh = unit & 31;                 // bh fastest
  const int bi = (kNBlk - 1) - (unit >> 5); // heavy q-blocks dispatched first
  const int b  = bh >> 4, h = bh & 15;

  const unsigned short* Qb  = qb  + ((size_t)bh * kS + (size_t)bi * kWin) * kHD;
  const unsigned short* Kb  = kb  + (size_t)bh * kS * kHD;
  const unsigned short* Vtb = vtb + (size_t)bh * kHD * kS;

  // Q fragments (B-operand of S^T = K·Q^T): n=query qt*16+q16, k=dim
  short8v qf[2][2];
#pragma unroll
  for (int qt = 0; qt < 2; ++qt)
#pragma unroll
    for (int ks = 0; ks < 2; ++ks)
      qf[qt][ks] = *(const short8v*)(Qb + (qt * 16 + q16) * kHD + ks * 32 + quad * 8);

  const f32x4 zero = {0.f, 0.f, 0.f, 0.f};
  f32x4 acc[2][4];
#pragma unroll
  for (int mt = 0; mt < 2; ++mt)
#pragma unroll
    for (int nt = 0; nt < 4; ++nt) acc[mt][nt] = zero;
  float dAcc0 = 0.f, dAcc1 = 0.f;
  const int swz = (q16 >> 2) & 3;

  for (int jb = 0; jb <= bi; ++jb) {
    unsigned short* esw = es[wave][jb & 1];
    const unsigned short* Kj = Kb + (size_t)jb * kWin * kHD;
    short8v kf[2][2];
#pragma unroll
    for (int kt = 0; kt < 2; ++kt)
#pragma unroll
      for (int ks = 0; ks < 2; ++ks)
        kf[kt][ks] = *(const short8v*)(Kj + (kt * 16 + q16) * kHD + ks * 32 + quad * 8);

    // S^T tiles: C[key=quad*4+r (+16kt)][query=q16 (+16qt)]
    f32x4 st[2][2];
#pragma unroll
    for (int kt = 0; kt < 2; ++kt)
#pragma unroll
      for (int qt = 0; qt < 2; ++qt) {
        f32x4 c = zero;
        c = __builtin_amdgcn_mfma_f32_16x16x32_bf16(kf[kt][0], qf[qt][0], c, 0, 0, 0);
        c = __builtin_amdgcn_mfma_f32_16x16x32_bf16(kf[kt][1], qf[qt][1], c, 0, 0, 0);
        st[kt][qt] = c;
      }

    // e = exp2(st)-1 (Q pre-scaled); accumulate denom; pack into Es
#pragma unroll
    for (int kt = 0; kt < 2; ++kt) {
      const int g = kt * 2 + (quad >> 1);
      const int col = ((g ^ swz) * 8) + (quad & 1) * 4;
#pragma unroll
      for (int qt = 0; qt < 2; ++qt) {
        const float e0 = __builtin_amdgcn_exp2f(st[kt][qt][0]) - 1.f;
        const float e1 = __builtin_amdgcn_exp2f(st[kt][qt][1]) - 1.f;
        const float e2 = __builtin_amdgcn_exp2f(st[kt][qt][2]) - 1.f;
        const float e3 = __builtin_amdgcn_exp2f(st[kt][qt][3]) - 1.f;
        if (qt == 0) dAcc0 += (e0 + e1) + (e2 + e3);
        else         dAcc1 += (e0 + e1) + (e2 + e3);
        const unsigned int w0 = (unsigned int)f2bf(e0) | ((unsigned int)f2bf(e1) << 16);
        const unsigned int w1 = (unsigned int)f2bf(e2) | ((unsigned int)f2bf(e3) << 16);
        const int q = qt * 16 + q16;
        *(unsigned int*)(esw + q * 32 + col)     = w0;
        *(unsigned int*)(esw + q * 32 + col + 2) = w1;
      }
    }

    // E A-fragments: m=q16(+16mt), k=key quad*8+j
    const short8v af0 = *(const short8v*)(esw + (q16)      * 32 + (quad ^ swz) * 8);
    const short8v af1 = *(const short8v*)(esw + (16 + q16) * 32 + (quad ^ swz) * 8);

    // E·V: B from Vt: n=dim nt*16+q16, k=key quad*8+j
#pragma unroll
    for (int nt = 0; nt < 4; ++nt) {
      const short8v vf = *(const short8v*)(Vtb + (size_t)(nt * 16 + q16) * kS +
                                           jb * kWin + quad * 8);
      acc[0][nt] = __builtin_amdgcn_mfma_f32_16x16x32_bf16(af0, vf, acc[0][nt], 0, 0, 0);
      acc[1][nt] = __builtin_amdgcn_mfma_f32_16x16x32_bf16(af1, vf, acc[1][nt], 0, 0, 0);
    }
  }

  // full denom per query (reduce over quads = keys)
  dAcc0 += __shfl_xor(dAcc0, 16); dAcc0 += __shfl_xor(dAcc0, 32);
  dAcc1 += __shfl_xor(dAcc1, 16); dAcc1 += __shfl_xor(dAcc1, 32);

  float vt[4];
#pragma unroll
  for (int nt = 0; nt < 4; ++nt) vt[nt] = vtotal[bh * kHD + nt * 16 + q16];

  unsigned short* outb = ctx + ((size_t)b * kS + (size_t)bi * kWin) * kH + h * kHD;
#pragma unroll
  for (int mt = 0; mt < 2; ++mt) {
    const float dA = mt ? dAcc1 : dAcc0;
#pragma unroll
    for (int r = 0; r < 4; ++r) {
      const int qrow = mt * 16 + quad * 4 + r;
      const float den = __shfl(dA, quad * 4 + r) + (float)kS;
      const float inv = 1.f / den;
      unsigned short* dst = outb + (size_t)qrow * kH;
#pragma unroll
      for (int nt = 0; nt < 4; ++nt)
        dst[nt * 16 + q16] = f2bf((acc[mt][nt][r] + vt[nt]) * inv);
    }
  }
}

}  // namespace

extern "C" void kernel_launch(void* const* d_in, const int* in_sizes, int n_in,
                              void* d_out, int out_size, void* d_ws, size_t ws_size,
                              hipStream_t stream) {
  const float* hs = (const float*)d_in[0];
  const float* Wq = (const float*)d_in[1];
  const float* bq = (const float*)d_in[2];
  const float* Wk = (const float*)d_in[3];
  const float* bk = (const float*)d_in[4];
  const float* Wv = (const float*)d_in[5];
  const float* bv = (const float*)d_in[6];
  const float* Wo = (const float*)d_in[7];
  const float* bo = (const float*)d_in[8];

  char* wsb = (char*)d_ws;
  unsigned short* hsb   = (unsigned short*)(wsb);                 //  8 MB [M][K] bf16
  unsigned short* wqkv  = hsb + (4u << 20);                       //  6 MB [3072][1024]
  unsigned short* wob   = hsb + (7u << 20);                       //  2 MB
  unsigned short* qbuf  = (unsigned short*)(wsb + (16u << 20));   //  8 MB [bh][s][d]
  unsigned short* kbuf  = (unsigned short*)(wsb + (24u << 20));   //  8 MB [bh][s][d]
  unsigned short* vtbuf = (unsigned short*)(wsb + (32u << 20));   //  8 MB [bh][d][s]
  unsigned short* ctxb  = (unsigned short*)(wsb + (40u << 20));   //  8 MB [M][H] bf16
  float*          vtot  = (float*)         (wsb + (48u << 20));   //  8 KB

  const int M = kB * kS;  // 4096

  cvt_bf16<<<4096, 256, 0, stream>>>(hs, Wq, Wk, Wv, Wo, hsb);
  // fused QKV: N = 3072, grid 24x32 = 768 wg (~3/CU)
  gemm_mfma<4, 1><<<dim3(3072 / 128, M / 128), 256, 0, stream>>>(
      hsb, wqkv, bq, bk, bv, nullptr, qbuf, kbuf, vtbuf, M, 3072, kH);
  vsum_t<<<kB * kNH, 256, 0, stream>>>(vtbuf, vtot);
  attn_wave<<<kNBlk * kB * kNH / 4, 256, 0, stream>>>(qbuf, kbuf, vtbuf, vtot, ctxb);
  // out-GEMM: 64x128 tiles, grid 8x64 = 512 wg (~2/CU)
  gemm_mfma<2, 0><<<dim3(kH / 128, M / 64), 256, 0, stream>>>(
      ctxb, wob, bo, nullptr, nullptr, (float*)d_out, nullptr, nullptr, nullptr,
      M, kH, kH);
}

// Round 5
// 231.718 us; speedup vs baseline: 5.1462x; 1.0700x over previous
//
#include <hip/hip_runtime.h>
#include <cstdint>

namespace {

constexpr int kS   = 2048;
constexpr int kNH  = 16;
constexpr int kHD  = 64;
constexpr int kH   = 1024;
constexpr int kB   = 2;
constexpr int kWin = 32;
constexpr int kNBlk = kS / kWin;  // 64
// exp(score/sqrt(64)) == exp2(score * log2(e)/8); folded into Q at projection
constexpr float kQScale = 0.18033688011112042f;

typedef __attribute__((ext_vector_type(8))) short short8v;          // 8 x bf16
typedef __attribute__((ext_vector_type(4))) float f32x4;            // MFMA C/D
typedef __attribute__((ext_vector_type(4))) unsigned short u16x4;
typedef __attribute__((ext_vector_type(8))) unsigned short u16x8;
typedef __attribute__((ext_vector_type(2))) unsigned int u32x2;

static __device__ __forceinline__ unsigned short f2bf(float f) {
  unsigned int u = __float_as_uint(f);
  return (unsigned short)((u + 0x7fffu + ((u >> 16) & 1u)) >> 16);
}
static __device__ __forceinline__ float bf2f(unsigned short b) {
  return __uint_as_float((unsigned int)b << 16);
}
static __device__ __forceinline__ void async16(const void* g, void* l) {
  __builtin_amdgcn_global_load_lds((__attribute__((address_space(1))) void*)(g),
                                   (__attribute__((address_space(3))) void*)(l),
                                   16, 0, 0);
}

// ---------------------------------------------------------------------------
// fp32 -> bf16 for hs (4M) and the four 1M weights, one dispatch.
// out layout: [hs 4M | Wq 1M | Wk 1M | Wv 1M | Wo 1M]  (Wq..Wv contiguous ->
// the fused QKV GEMM treats them as one [3072][1024] matrix)
// ---------------------------------------------------------------------------
__global__ __launch_bounds__(256) void cvt_bf16(
    const float* __restrict__ hs, const float* __restrict__ Wq,
    const float* __restrict__ Wk, const float* __restrict__ Wv,
    const float* __restrict__ Wo, unsigned short* __restrict__ out)
{
  const size_t idx = ((size_t)blockIdx.x * 256 + threadIdx.x) * 8;
  const int seg = (int)(idx >> 20);
  const size_t off = idx & ((1u << 20) - 1);
  const float* src;
  if (seg < 4)       src = hs + idx;
  else if (seg == 4) src = Wq + off;
  else if (seg == 5) src = Wk + off;
  else if (seg == 6) src = Wv + off;
  else               src = Wo + off;
  const float4 f0 = *(const float4*)(src);
  const float4 f1 = *(const float4*)(src + 4);
  u16x8 pk;
  pk[0] = f2bf(f0.x); pk[1] = f2bf(f0.y); pk[2] = f2bf(f0.z); pk[3] = f2bf(f0.w);
  pk[4] = f2bf(f1.x); pk[5] = f2bf(f1.y); pk[6] = f2bf(f1.z); pk[7] = f2bf(f1.w);
  *(u16x8*)(out + idx) = pk;
}

// ---------------------------------------------------------------------------
// bf16 MFMA GEMM, templated block-M (MT*32 rows) x 128 cols x 32 k-tile.
//   EPI 0: C fp32 [M,N] += bias                       (out-GEMM)
//   EPI 1: fused QKV routing: col>>10 selects matrix:
//          0 -> Q bf16 [bh][s][d] scaled by kQScale
//          1 -> K bf16 [bh][s][d]
//          2 -> V bf16 transposed [bh][d][s]
// ---------------------------------------------------------------------------
template <int MT, int EPI>
__global__ __launch_bounds__(256) void gemm_mfma(
    const unsigned short* __restrict__ A, const unsigned short* __restrict__ W,
    const float* __restrict__ b0, const float* __restrict__ b1,
    const float* __restrict__ b2, float* __restrict__ Cf,
    unsigned short* __restrict__ Dq, unsigned short* __restrict__ Dk,
    unsigned short* __restrict__ Dv, int M, int N, int K)
{
  constexpr int BMr = MT * 32;
  constexpr int AG  = MT / 2;           // 16-row staging groups per wave (A)
  __shared__ unsigned short As[BMr * 32];
  __shared__ unsigned short Ws[128 * 32];
  const int tid  = threadIdx.x;
  const int wave = tid >> 6, lane = tid & 63;
  const int q16  = lane & 15, quad = lane >> 4;
  const int wm   = wave & 1,  wn   = wave >> 1;
  const int bm = blockIdx.y * BMr, bn = blockIdx.x * 128;

  const int lrow   = lane >> 2;
  const int lchunk = (lane & 3) ^ ((lane >> 3) & 3);  // content swizzle

  const unsigned short* gA[AG];
  unsigned short* lA[AG];
#pragma unroll
  for (int g = 0; g < AG; ++g) {
    gA[g] = A + (size_t)(bm + wave * 16 * AG + g * 16 + lrow) * K + lchunk * 8;
    lA[g] = As + (wave * 16 * AG + g * 16) * 32;
  }
  const unsigned short* gW0 = W + (size_t)(bn + wave * 32 + lrow) * K + lchunk * 8;
  const unsigned short* gW1 = gW0 + (size_t)16 * K;
  unsigned short* lW0 = Ws + (wave * 32) * 32;
  unsigned short* lW1 = lW0 + 16 * 32;

  const int swz = quad ^ ((q16 >> 1) & 3);
  const unsigned short* fA = As + (wm * (MT * 16) + q16) * 32 + swz * 8;
  const unsigned short* fB = Ws + (wn * 64 + q16) * 32 + swz * 8;

  const f32x4 zero = {0.f, 0.f, 0.f, 0.f};
  f32x4 acc[MT][4];
#pragma unroll
  for (int i = 0; i < MT; ++i)
#pragma unroll
    for (int j = 0; j < 4; ++j) acc[i][j] = zero;

  for (int k0 = 0; k0 < K; k0 += 32) {
    __syncthreads();
#pragma unroll
    for (int g = 0; g < AG; ++g) { async16(gA[g], lA[g]); gA[g] += 32; }
    async16(gW0, lW0);
    async16(gW1, lW1);
    gW0 += 32; gW1 += 32;
    __syncthreads();

    short8v a[MT], b[4];
#pragma unroll
    for (int t = 0; t < MT; ++t) a[t] = *(const short8v*)(fA + t * 16 * 32);
#pragma unroll
    for (int t = 0; t < 4; ++t)  b[t] = *(const short8v*)(fB + t * 16 * 32);
#pragma unroll
    for (int mt = 0; mt < MT; ++mt)
#pragma unroll
      for (int nt = 0; nt < 4; ++nt)
        acc[mt][nt] = __builtin_amdgcn_mfma_f32_16x16x32_bf16(a[mt], b[nt], acc[mt][nt], 0, 0, 0);
  }

  // epilogue. C/D layout: col = lane&15 (n), row = quad*4 + reg (m).
#pragma unroll
  for (int nt = 0; nt < 4; ++nt) {
    const int col = bn + wn * 64 + nt * 16 + q16;
#pragma unroll
    for (int mt = 0; mt < MT; ++mt) {
      const int row0 = bm + wm * (MT * 16) + mt * 16 + quad * 4;
      const f32x4 av = acc[mt][nt];
      if (EPI == 0) {
        const float bv = b0[col];
#pragma unroll
        for (int r = 0; r < 4; ++r)
          Cf[(size_t)(row0 + r) * N + col] = av[r] + bv;
      } else {
        const int mat = col >> 10, c = col & 1023;
        const int b = row0 >> 11, s0 = row0 & 2047;
        const int h = c >> 6, d = c & 63;
        const size_t bhslot = (size_t)(b * kNH + h);
        if (mat == 0) {
          const float bv = b0[c];
          unsigned short* base = Dq + ((bhslot * kS + s0) * kHD + d);
#pragma unroll
          for (int r = 0; r < 4; ++r) base[(size_t)r * kHD] = f2bf((av[r] + bv) * kQScale);
        } else if (mat == 1) {
          const float bv = b1[c];
          unsigned short* base = Dk + ((bhslot * kS + s0) * kHD + d);
#pragma unroll
          for (int r = 0; r < 4; ++r) base[(size_t)r * kHD] = f2bf(av[r] + bv);
        } else {
          const float bv = b2[c];
          u16x4 pk;
          pk[0] = f2bf(av[0] + bv); pk[1] = f2bf(av[1] + bv);
          pk[2] = f2bf(av[2] + bv); pk[3] = f2bf(av[3] + bv);
          *(u16x4*)(Dv + (bhslot * kHD + d) * kS + s0) = pk;
        }
      }
    }
  }
}

// ---------------------------------------------------------------------------
// vrest[bh][bi][d] = sum over masked (future) blocks: sum_{jb>bi} block-sum.
// One block per bh; thread = (d 0..63, part 0..3); part owns 16 jb blocks.
// ---------------------------------------------------------------------------
__global__ __launch_bounds__(256) void vprefix_kernel(
    const unsigned short* __restrict__ vt, float* __restrict__ vrest)
{
  __shared__ float bsum[64][64];   // [jb][d]
  __shared__ float ptot[4][64];
  const int bh = blockIdx.x;
  const int d = threadIdx.x & 63, part = threadIdx.x >> 6;
  const unsigned short* base = vt + ((size_t)bh * kHD + d) * kS;
#pragma unroll 4
  for (int j = 0; j < 16; ++j) {
    const int jb = part * 16 + j;
    const unsigned short* p = base + jb * kWin;
    float s = 0.f;
#pragma unroll
    for (int i = 0; i < 4; ++i) {
      const u16x8 v = *(const u16x8*)(p + i * 8);
#pragma unroll
      for (int e = 0; e < 8; ++e) s += bf2f(v[e]);
    }
    bsum[jb][d] = s;
  }
  __syncthreads();
  float t = 0.f;
#pragma unroll
  for (int j = 0; j < 16; ++j) t += bsum[part * 16 + j][d];
  ptot[part][d] = t;
  __syncthreads();
  float s = 0.f;
  for (int p2 = part + 1; p2 < 4; ++p2) s += ptot[p2][d];
#pragma unroll
  for (int j = 15; j >= 0; --j) {
    const int bi = part * 16 + j;
    vrest[((size_t)bh * kNBlk + bi) * kHD + d] = s;
    s += bsum[bi][d];
  }
}

// ---------------------------------------------------------------------------
// MFMA attention, 4-wave cooperative unit per (bh, qblock); wave w handles
// jb = w, w+4, ...  Q pre-scaled so e' = exp2(st).  Identity:
//   ctx_i = (sum_{jb<=bi} e'_ij v_j + vrest[bi]) / (sum e'_ij + 32*(63-bi))
// Denominator computed by an extra MFMA against a constant ones-fragment.
// ---------------------------------------------------------------------------
__global__ __launch_bounds__(256, 4) void attn_mfma(
    const unsigned short* __restrict__ qb, const unsigned short* __restrict__ kb,
    const unsigned short* __restrict__ vtb, const float* __restrict__ vrest,
    unsigned short* __restrict__ ctx)
{
  __shared__ union SM {
    unsigned short es[4][1024];                            // per-wave E, 8KB
    struct { float part[2][2048]; float den[4][32]; } m;   // merge, 16.5KB
  } sm;

  const int tid  = threadIdx.x;
  const int wave = tid >> 6;
  const int lane = tid & 63;
  const int q16  = lane & 15;
  const int quad = lane >> 4;
  const int bh = blockIdx.x & 31;                  // bh fastest -> XCD locality
  const int bi = (kNBlk - 1) - (blockIdx.x >> 5);  // heavy q-blocks first
  const int b  = bh >> 4, h = bh & 15;

  const unsigned short* Qb  = qb  + ((size_t)bh * kS + (size_t)bi * kWin) * kHD;
  const unsigned short* Kb  = kb  + (size_t)bh * kS * kHD;
  const unsigned short* Vtb = vtb + (size_t)bh * kHD * kS;

  // Q fragments (B-operand of S^T = K·Q^T): n=query qt*16+q16, k=dim
  short8v qf[2][2];
#pragma unroll
  for (int qt = 0; qt < 2; ++qt)
#pragma unroll
    for (int ks = 0; ks < 2; ++ks)
      qf[qt][ks] = *(const short8v*)(Qb + (qt * 16 + q16) * kHD + ks * 32 + quad * 8);

  // constant ones B-fragment: virtual V-row 0 (n==0) is all 1.0 bf16
  short8v ones;
#pragma unroll
  for (int i = 0; i < 8; ++i) ones[i] = (q16 == 0) ? (short)0x3F80 : (short)0;

  const f32x4 zero = {0.f, 0.f, 0.f, 0.f};
  f32x4 acc[2][4];
#pragma unroll
  for (int mt = 0; mt < 2; ++mt)
#pragma unroll
    for (int nt = 0; nt < 4; ++nt) acc[mt][nt] = zero;
  f32x4 accd[2] = {zero, zero};

  unsigned short* esw = sm.es[wave];
  const int swz = (q16 >> 2) & 3;

  for (int jb = wave; jb <= bi; jb += 4) {
    const unsigned short* Kj = Kb + (size_t)jb * kWin * kHD;
    // K fragments (A-operand): m=key kt*16+q16, k=dim
    short8v kf[2][2];
#pragma unroll
    for (int kt = 0; kt < 2; ++kt)
#pragma unroll
      for (int ks = 0; ks < 2; ++ks)
        kf[kt][ks] = *(const short8v*)(Kj + (kt * 16 + q16) * kHD + ks * 32 + quad * 8);
    // V fragments hoisted early: latency covered by QK + exp phase
    short8v vf[4];
#pragma unroll
    for (int nt = 0; nt < 4; ++nt)
      vf[nt] = *(const short8v*)(Vtb + (size_t)(nt * 16 + q16) * kS + jb * kWin + quad * 8);

    // S^T tiles: C[key=quad*4+r (+16kt)][query=q16 (+16qt)]
    f32x4 st[2][2];
#pragma unroll
    for (int kt = 0; kt < 2; ++kt)
#pragma unroll
      for (int qt = 0; qt < 2; ++qt) {
        f32x4 c = zero;
        c = __builtin_amdgcn_mfma_f32_16x16x32_bf16(kf[kt][0], qf[qt][0], c, 0, 0, 0);
        c = __builtin_amdgcn_mfma_f32_16x16x32_bf16(kf[kt][1], qf[qt][1], c, 0, 0, 0);
        st[kt][qt] = c;
      }

    // e' = exp2(st); pack 2x bf16 per dword via +0x8000 round + v_perm
#pragma unroll
    for (int kt = 0; kt < 2; ++kt) {
      const int g = kt * 2 + (quad >> 1);
      const int col = ((g ^ swz) * 8) + (quad & 1) * 4;   // shorts; 8B aligned
#pragma unroll
      for (int qt = 0; qt < 2; ++qt) {
        const unsigned int r0 = __float_as_uint(__builtin_amdgcn_exp2f(st[kt][qt][0])) + 0x8000u;
        const unsigned int r1 = __float_as_uint(__builtin_amdgcn_exp2f(st[kt][qt][1])) + 0x8000u;
        const unsigned int r2 = __float_as_uint(__builtin_amdgcn_exp2f(st[kt][qt][2])) + 0x8000u;
        const unsigned int r3 = __float_as_uint(__builtin_amdgcn_exp2f(st[kt][qt][3])) + 0x8000u;
        u32x2 w;
        w[0] = __builtin_amdgcn_perm(r1, r0, 0x07060302u);
        w[1] = __builtin_amdgcn_perm(r3, r2, 0x07060302u);
        *(u32x2*)(esw + (qt * 16 + q16) * 32 + col) = w;
      }
    }

    // E A-fragments: m=q16(+16mt), k=key quad*8+j
    const short8v af0 = *(const short8v*)(esw + (q16)      * 32 + (quad ^ swz) * 8);
    const short8v af1 = *(const short8v*)(esw + (16 + q16) * 32 + (quad ^ swz) * 8);

#pragma unroll
    for (int nt = 0; nt < 4; ++nt) {
      acc[0][nt] = __builtin_amdgcn_mfma_f32_16x16x32_bf16(af0, vf[nt], acc[0][nt], 0, 0, 0);
      acc[1][nt] = __builtin_amdgcn_mfma_f32_16x16x32_bf16(af1, vf[nt], acc[1][nt], 0, 0, 0);
    }
    accd[0] = __builtin_amdgcn_mfma_f32_16x16x32_bf16(af0, ones, accd[0], 0, 0, 0);
    accd[1] = __builtin_amdgcn_mfma_f32_16x16x32_bf16(af1, ones, accd[1], 0, 0, 0);
  }

  __syncthreads();  // es phase done before aliasing as part/den
  // denom sits in lanes q16==0: row (query) = quad*4+r, per mt tile
  if (q16 == 0) {
#pragma unroll
    for (int mt = 0; mt < 2; ++mt)
#pragma unroll
      for (int r = 0; r < 4; ++r)
        sm.m.den[wave][mt * 16 + quad * 4 + r] = accd[mt][r];
  }
  if (wave < 2) {
    float* p = sm.m.part[wave];
#pragma unroll
    for (int mt = 0; mt < 2; ++mt)
#pragma unroll
      for (int nt = 0; nt < 4; ++nt)
#pragma unroll
        for (int r = 0; r < 4; ++r)
          p[((mt * 4 + nt) * 4 + r) * 64 + lane] = acc[mt][nt][r];
  }
  __syncthreads();
  if (wave >= 2) {
    float* p = sm.m.part[wave - 2];
#pragma unroll
    for (int mt = 0; mt < 2; ++mt)
#pragma unroll
      for (int nt = 0; nt < 4; ++nt)
#pragma unroll
        for (int r = 0; r < 4; ++r)
          p[((mt * 4 + nt) * 4 + r) * 64 + lane] += acc[mt][nt][r];
  }
  __syncthreads();

  // finalize: wave w owns dim-tile nt==w
  {
    const int nt = wave;
    const int dim = nt * 16 + q16;
    const float vr = vrest[((size_t)bh * kNBlk + bi) * kHD + dim];
    const float nrest = 32.0f * (float)((kNBlk - 1) - bi);
    unsigned short* outb = ctx + ((size_t)b * kS + (size_t)bi * kWin) * kH + h * kHD;
#pragma unroll
    for (int mt = 0; mt < 2; ++mt) {
#pragma unroll
      for (int r = 0; r < 4; ++r) {
        const int idx = ((mt * 4 + nt) * 4 + r) * 64 + lane;
        const int qrow = mt * 16 + quad * 4 + r;
        const float den = sm.m.den[0][qrow] + sm.m.den[1][qrow] +
                          sm.m.den[2][qrow] + sm.m.den[3][qrow] + nrest;
        outb[(size_t)qrow * kH + dim] =
            f2bf((sm.m.part[0][idx] + sm.m.part[1][idx] + vr) / den);
      }
    }
  }
}

}  // namespace

extern "C" void kernel_launch(void* const* d_in, const int* in_sizes, int n_in,
                              void* d_out, int out_size, void* d_ws, size_t ws_size,
                              hipStream_t stream) {
  const float* hs = (const float*)d_in[0];
  const float* Wq = (const float*)d_in[1];
  const float* bq = (const float*)d_in[2];
  const float* Wk = (const float*)d_in[3];
  const float* bk = (const float*)d_in[4];
  const float* Wv = (const float*)d_in[5];
  const float* bv = (const float*)d_in[6];
  const float* Wo = (const float*)d_in[7];
  const float* bo = (const float*)d_in[8];

  char* wsb = (char*)d_ws;
  unsigned short* hsb   = (unsigned short*)(wsb);                 //  8 MB [M][K] bf16
  unsigned short* wqkv  = hsb + (4u << 20);                       //  6 MB [3072][1024]
  unsigned short* wob   = hsb + (7u << 20);                       //  2 MB
  unsigned short* qbuf  = (unsigned short*)(wsb + (16u << 20));   //  8 MB [bh][s][d]
  unsigned short* kbuf  = (unsigned short*)(wsb + (24u << 20));   //  8 MB [bh][s][d]
  unsigned short* vtbuf = (unsigned short*)(wsb + (32u << 20));   //  8 MB [bh][d][s]
  unsigned short* ctxb  = (unsigned short*)(wsb + (40u << 20));   //  8 MB [M][H] bf16
  float*          vrest = (float*)         (wsb + (48u << 20));   // 512 KB [bh][bi][d]

  const int M = kB * kS;  // 4096

  cvt_bf16<<<4096, 256, 0, stream>>>(hs, Wq, Wk, Wv, Wo, hsb);
  // fused QKV: N = 3072, grid 24x32 = 768 wg (~3/CU)
  gemm_mfma<4, 1><<<dim3(3072 / 128, M / 128), 256, 0, stream>>>(
      hsb, wqkv, bq, bk, bv, nullptr, qbuf, kbuf, vtbuf, M, 3072, kH);
  vprefix_kernel<<<kB * kNH, 256, 0, stream>>>(vtbuf, vrest);
  attn_mfma<<<kNBlk * kB * kNH, 256, 0, stream>>>(qbuf, kbuf, vtbuf, vrest, ctxb);
  // out-GEMM: 64x128 tiles, grid 8x64 = 512 wg (~2/CU)
  gemm_mfma<2, 0><<<dim3(kH / 128, M / 64), 256, 0, stream>>>(
      ctxb, wob, bo, nullptr, nullptr, (float*)d_out, nullptr, nullptr, nullptr,
      M, kH, kH);
}